// Round 2
// baseline (98.395 us; speedup 1.0000x reference)
//
#include <hip/hip_runtime.h>
#include <hip/hip_bf16.h>
#include <cmath>
#include <cstdint>

#define Bsz   4096
#define INsz  512
#define OUTsz 512
#define NRING 16
#define KTOT  8704          /* IN*(NR+1): residual folded in as 17th slot */
#define SPLITK 4
#define KSPL  2176          /* KTOT/SPLITK */
#define NKST  34            /* KSPL/BK */
#define BM 128
#define BN 128
#define BK 64

using short8 = __attribute__((ext_vector_type(8))) short;
using f32x4  = __attribute__((ext_vector_type(4))) float;

struct PhysConsts {
  double c1rev[NRING];   // (L/WL0)*(neff_r - NG)  [revolutions]
  double c2rev;          // L*NG                   [rev * m]
  float p, q, s, pad;    // num = p - q*c ; den = s - q*c
};

__device__ __forceinline__ unsigned short f2bf(float f) {
  union { float f; unsigned int u; } v; v.f = f;
  unsigned int u = v.u + 0x7FFFu + ((v.u >> 16) & 1u);  // RNE
  return (unsigned short)(u >> 16);
}

__device__ __forceinline__ float cos2pi(float fr) {
#if __has_builtin(__builtin_amdgcn_cosf)
  return __builtin_amdgcn_cosf(fr);     // v_cos_f32: cos(2*pi*fr)
#else
  return __cosf(fr * 6.28318530717958647692f);
#endif
}

// ---- pack A': [B][KTOT] bf16, k = n*512 + i (n<16: basis, n=16: raw x) ----
__global__ __launch_bounds__(256) void pack_a_kernel(
    const float* __restrict__ x, unsigned short* __restrict__ Ap, PhysConsts pc) {
  const int tid = threadIdx.x;
  const int bid = blockIdx.x;
  const int b = bid >> 1;
  const int i = ((bid & 1) << 8) | tid;
  const float xv = x[(size_t)b * INsz + i];
  const float xc = fminf(fmaxf(xv, -1.0f), 1.0f);
  const double wl = 1546.0e-9 + (0.5 * ((double)xc + 1.0)) * 8.0e-9;
  const double t  = pc.c2rev / wl;          // rev = c1rev[r] + t
  unsigned short* row = Ap + (size_t)b * KTOT + i;
#pragma unroll
  for (int r = 0; r < NRING; ++r) {
    double rev = pc.c1rev[r] + t;
    float fr = (float)(rev - floor(rev));
    float c = cos2pi(fr);
    float num = __builtin_fmaf(-pc.q, c, pc.p);
    float den = __builtin_fmaf(-pc.q, c, pc.s);
    row[(size_t)r * INsz] = f2bf(num / den);
  }
  row[(size_t)NRING * INsz] = f2bf(xv);     // residual slot uses UNclipped x
}

// ---- pack B'^T: [OUT][KTOT] bf16, same k map ----
__global__ __launch_bounds__(256) void pack_b_kernel(
    const float* __restrict__ coeffs, const float* __restrict__ bw,
    unsigned short* __restrict__ Bt) {
  const int tid = threadIdx.x;
  const int bid = blockIdx.x;
  const int o = bid >> 1;
  const int i = ((bid & 1) << 8) | tid;
  const float* cp = coeffs + ((size_t)i * OUTsz + o) * NRING;  // 64B contiguous
  unsigned short* row = Bt + (size_t)o * KTOT + i;
#pragma unroll
  for (int r = 0; r < NRING; ++r) row[(size_t)r * INsz] = f2bf(cp[r]);
  row[(size_t)NRING * INsz] = f2bf(bw[(size_t)i * OUTsz + o]);
}

__device__ __forceinline__ void gl_lds16(const void* g, void* l) {
  __builtin_amdgcn_global_load_lds(
      (const __attribute__((address_space(1))) void*)g,
      (__attribute__((address_space(3))) void*)l, 16, 0, 0);
}

// ---- split-K bf16 MFMA GEMM: D[4096][512] partials ----
__global__ __launch_bounds__(256, 2) void gemm_kernel(
    const unsigned short* __restrict__ Ap, const unsigned short* __restrict__ Bt,
    float* __restrict__ part) {
  __shared__ __align__(16) unsigned short As[BM * BK];  // [128][64]
  __shared__ __align__(16) unsigned short Bs[BN * BK];  // [128][64] (B^T tile)
  const int tid  = threadIdx.x;
  const int lane = tid & 63;
  const int w    = tid >> 6;
  const int bid  = blockIdx.x;
  const int cb   = bid & 3;          // N/BN = 4
  const int rb   = (bid >> 2) & 31;  // M/BM = 32
  const int ks   = bid >> 7;         // split index
  const int brow = rb * BM;
  const int bcol = cb * BN;

  // staging: 4 passes x (4 waves x 64 lanes x 16B) covers 128 rows x 128B
  const unsigned short* ga = Ap + (size_t)(brow + w * 8 + (lane >> 3)) * KTOT
                                + (size_t)ks * KSPL + (lane & 7) * 8;
  const unsigned short* gb = Bt + (size_t)(bcol + w * 8 + (lane >> 3)) * KTOT
                                + (size_t)ks * KSPL + (lane & 7) * 8;
  char* lA = (char*)As + w * 8 * 128;   // wave-uniform; HW adds lane*16
  char* lB = (char*)Bs + w * 8 * 128;

  f32x4 acc[4][4];
#pragma unroll
  for (int m = 0; m < 4; ++m)
#pragma unroll
    for (int n = 0; n < 4; ++n) acc[m][n] = (f32x4){0.f, 0.f, 0.f, 0.f};

  const int wr = w >> 1, wc = w & 1;   // 2x2 waves, 64x64 each
  const unsigned short* rA = As + ((wr * 64) + (lane & 15)) * BK + ((lane >> 4) * 8);
  const unsigned short* rB = Bs + ((wc * 64) + (lane & 15)) * BK + ((lane >> 4) * 8);

  for (int kt = 0; kt < NKST; ++kt) {
    __syncthreads();
#pragma unroll
    for (int p = 0; p < 4; ++p) {
      gl_lds16(ga + (size_t)p * 32 * KTOT + kt * 64, lA + p * 32 * 128);
      gl_lds16(gb + (size_t)p * 32 * KTOT + kt * 64, lB + p * 32 * 128);
    }
    __syncthreads();   // compiler emits vmcnt(0) drain before barrier
#pragma unroll
    for (int kk = 0; kk < 2; ++kk) {
      short8 af[4], bf[4];
#pragma unroll
      for (int m = 0; m < 4; ++m)
        af[m] = *reinterpret_cast<const short8*>(rA + m * 16 * BK + kk * 32);
#pragma unroll
      for (int n = 0; n < 4; ++n)
        bf[n] = *reinterpret_cast<const short8*>(rB + n * 16 * BK + kk * 32);
#pragma unroll
      for (int m = 0; m < 4; ++m)
#pragma unroll
        for (int n = 0; n < 4; ++n)
          acc[m][n] = __builtin_amdgcn_mfma_f32_16x16x32_bf16(af[m], bf[n], acc[m][n], 0, 0, 0);
    }
  }

  float* po = part + (size_t)ks * ((size_t)Bsz * OUTsz);
  const int r0 = brow + wr * 64 + ((lane >> 4) * 4);
  const int c0 = bcol + wc * 64 + (lane & 15);
#pragma unroll
  for (int m = 0; m < 4; ++m)
#pragma unroll
    for (int n = 0; n < 4; ++n)
#pragma unroll
      for (int r = 0; r < 4; ++r)
        po[(size_t)(r0 + m * 16 + r) * OUTsz + (c0 + n * 16)] = acc[m][n][r];
}

// ---- reduce 4 split-K partials + kl ----
__global__ __launch_bounds__(256) void reduce_kernel(
    const f32x4* __restrict__ part, float* __restrict__ out) {
  const size_t idx = (size_t)blockIdx.x * 256 + threadIdx.x;
  const size_t stride = (size_t)Bsz * OUTsz / 4;
  f32x4 v = part[idx] + part[idx + stride] + part[idx + 2 * stride] + part[idx + 3 * stride];
  reinterpret_cast<f32x4*>(out)[idx] = v;
  if (idx == 0) out[(size_t)Bsz * OUTsz] = 0.0f;   // kl
}

extern "C" void kernel_launch(void* const* d_in, const int* in_sizes, int n_in,
                              void* d_out, int out_size, void* d_ws, size_t ws_size,
                              hipStream_t stream) {
  const float* x      = (const float*)d_in[0];
  const float* coeffs = (const float*)d_in[1];
  const float* bw     = (const float*)d_in[2];
  float* out = (float*)d_out;

  unsigned short* Ap = (unsigned short*)d_ws;                         // 71,303,168 B
  unsigned short* Bt = (unsigned short*)((char*)d_ws + (size_t)Bsz * KTOT * 2);
  float* part = (float*)((char*)d_ws + (size_t)Bsz * KTOT * 2
                                     + (size_t)OUTsz * KTOT * 2);     // 33,554,432 B

  PhysConsts pc;
  {
    const double PI  = 3.14159265358979323846;
    const double Lc  = 2.0 * PI * 30.0e-6;
    const double WL0 = 1550.0e-9;
    const double Aamp = pow(10.0, -3.0 * (Lc * 100.0) / 20.0);
    const double Rt   = sqrt(0.8);
    pc.c2rev = Lc * 4.2;
    for (int r = 0; r < NRING; ++r) {
      double off  = -PI + r * (2.0 * PI / 15.0);
      double neff = 2.34 + off * WL0 / (2.0 * PI * Lc);
      pc.c1rev[r] = (Lc / WL0) * (neff - 4.2);
    }
    pc.p = (float)(Aamp * Aamp + 0.8);
    pc.q = (float)(2.0 * Rt * Aamp);
    pc.s = (float)(1.0 + 0.8 * Aamp * Aamp);
    pc.pad = 0.f;
  }

  hipLaunchKernelGGL(pack_a_kernel, dim3((Bsz * INsz) / 256), dim3(256), 0, stream, x, Ap, pc);
  hipLaunchKernelGGL(pack_b_kernel, dim3((INsz * OUTsz) / 256), dim3(256), 0, stream, coeffs, bw, Bt);
  hipLaunchKernelGGL(gemm_kernel, dim3(32 * 4 * SPLITK), dim3(256), 0, stream, Ap, Bt, part);
  hipLaunchKernelGGL(reduce_kernel, dim3((Bsz * OUTsz / 4) / 256), dim3(256), 0, stream,
                     (const f32x4*)part, out);
}

// Round 3
// 79.184 us; speedup vs baseline: 1.2426x; 1.2426x over previous
//
#include <hip/hip_runtime.h>
#include <hip/hip_bf16.h>
#include <cmath>
#include <cstdint>

#define Bsz   4096
#define INsz  512
#define OUTsz 512
#define NRING 16
#define KTOT  8704          /* IN*(NR+1): residual folded in as 17th slot */
#define SPLITK 4
#define BM 128
#define BN 128
#define BK 64

using short8 = __attribute__((ext_vector_type(8))) short;
using f32x4  = __attribute__((ext_vector_type(4))) float;

struct RC {
  float Cr[NRING];    // cos(2*pi*rev0_r)
  float Snr[NRING];   // -sin(2*pi*rev0_r)
  float K2, qn, s, P; // h=K2*xc*rcp(wl); den=fma(qn,c,s); T=fma(P,rcp(den),1)
};

__device__ __forceinline__ unsigned short f2bf_manual(float f) {
  union { float f; unsigned int u; } v; v.f = f;
  unsigned int u = v.u + 0x7FFFu + ((v.u >> 16) & 1u);  // RNE
  return (unsigned short)(u >> 16);
}
__device__ __forceinline__ unsigned short f2bf(float f) {
  __hip_bfloat16 h = __float2bfloat16(f);               // native cvt (RNE)
  return *reinterpret_cast<unsigned short*>(&h);
}
__device__ __forceinline__ float fastrcp(float x) {
#if __has_builtin(__builtin_amdgcn_rcpf)
  return __builtin_amdgcn_rcpf(x);
#else
  return 1.0f / x;
#endif
}
__device__ __forceinline__ float fastfract(float x) {
#if __has_builtin(__builtin_amdgcn_fractf)
  return __builtin_amdgcn_fractf(x);
#else
  return x - floorf(x);
#endif
}
__device__ __forceinline__ float cos2pi(float fr) {
#if __has_builtin(__builtin_amdgcn_cosf)
  return __builtin_amdgcn_cosf(fr);
#else
  return __cosf(fr * 6.28318530717958647692f);
#endif
}
__device__ __forceinline__ float sin2pi(float fr) {
#if __has_builtin(__builtin_amdgcn_sinf)
  return __builtin_amdgcn_sinf(fr);
#else
  return __sinf(fr * 6.28318530717958647692f);
#endif
}

// ---- pack B'^T: [OUT][KTOT] bf16, k = n*512 + i ----
__global__ __launch_bounds__(256) void pack_b_kernel(
    const float* __restrict__ coeffs, const float* __restrict__ bw,
    unsigned short* __restrict__ Bt) {
  const int tid = threadIdx.x;
  const int bid = blockIdx.x;
  const int o = bid >> 1;
  const int i = ((bid & 1) << 8) | tid;
  const float* cp = coeffs + ((size_t)i * OUTsz + o) * NRING;  // 64B contiguous
  unsigned short* row = Bt + (size_t)o * KTOT + i;
#pragma unroll
  for (int r = 0; r < NRING; ++r) row[(size_t)r * INsz] = f2bf_manual(cp[r]);
  row[(size_t)NRING * INsz] = f2bf_manual(bw[(size_t)i * OUTsz + o]);
}

__device__ __forceinline__ void gl_lds16(const void* g, void* l) {
  __builtin_amdgcn_global_load_lds(
      (const __attribute__((address_space(1))) void*)g,
      (__attribute__((address_space(3))) void*)l, 16, 0, 0);
}

// ---- fused basis-gen + split-K bf16 MFMA GEMM ----
// K ordering: k = n*512 + i. Block: BM=128 rows x BN=128 cols, ks owns
// i-range [ks*128, ks*128+128) => K-work 17 rings x 128 i = 2176.
__global__ __launch_bounds__(256, 2) void gemm_fused_kernel(
    const float* __restrict__ x, const unsigned short* __restrict__ Bt,
    float* __restrict__ part, RC rc) {
  __shared__ __align__(16) unsigned short As[BM * BK];  // swizzled [128][64]
  __shared__ __align__(16) unsigned short Bs[BN * BK];  // swizzled-by-source [128][64]
  const int tid  = threadIdx.x;
  const int lane = tid & 63;
  const int w    = tid >> 6;
  const int bid  = blockIdx.x;
  const int cb   = bid & 3;
  const int rb   = (bid >> 2) & 31;
  const int ks   = bid >> 7;
  const int brow = rb * BM;
  const int bcol = cb * BN;

  // --- A-gen cell ownership: row r (0..127), column half ch (32 i's) ---
  const int r  = tid & 127;
  const int ch = tid >> 7;
  int wb[4];                               // swizzled ds_write byte offsets
#pragma unroll
  for (int g = 0; g < 4; ++g)
    wb[g] = r * 128 + (((ch * 4 + g) ^ (r & 7)) * 16);
  const float* gx = x + (size_t)(brow + r) * INsz + ks * 128 + ch * 32;

  // --- B staging: pre-swizzled per-lane global source (rule 21 / m201) ---
  // LDS row = p*32 + w*8 + (lane>>3); linear dest octet = lane&7;
  // source octet = (lane&7) ^ (row&7) = (lane&7) ^ ((lane>>3)&7).
  const int cg = (lane & 7) ^ ((lane >> 3) & 7);
  const unsigned short* gb0 = Bt + (size_t)(bcol + w * 8 + (lane >> 3)) * KTOT + cg * 8;
  char* lB = (char*)Bs + w * 1024;         // + p*4096; HW adds lane*16

  // --- fragment read addresses (swizzled: slot = octet ^ (row&7)) ---
  const int wr = w >> 1, wc = w & 1;       // 2x2 waves, 64x64 out each
  const int l7 = lane & 7;
  const int rowA = wr * 64 + (lane & 15);
  const int rowB = wc * 64 + (lane & 15);
  const char* pA0 = (char*)As + rowA * 128 + ((((lane >> 4) + 0) ^ l7) * 16);
  const char* pA1 = (char*)As + rowA * 128 + ((((lane >> 4) + 4) ^ l7) * 16);
  const char* pB0 = (char*)Bs + rowB * 128 + ((((lane >> 4) + 0) ^ l7) * 16);
  const char* pB1 = (char*)Bs + rowB * 128 + ((((lane >> 4) + 4) ^ l7) * 16);

  f32x4 acc[4][4];
#pragma unroll
  for (int m = 0; m < 4; ++m)
#pragma unroll
    for (int n = 0; n < 4; ++n) acc[m][n] = (f32x4){0.f, 0.f, 0.f, 0.f};

  for (int is = 0; is < 2; ++is) {
    // ---- per-(b,i) prep: one sin/cos per cell, reused by all 16 rings ----
    float cth[32], sth[32], xr[32];
#pragma unroll
    for (int j = 0; j < 8; ++j) {
      f32x4 v = *reinterpret_cast<const f32x4*>(gx + is * 64 + j * 4);
#pragma unroll
      for (int e = 0; e < 4; ++e) {
        const int cc = j * 4 + e;
        float xv = v[e];
        xr[cc] = xv;
        float xc = fminf(fmaxf(xv, -1.0f), 1.0f);
        float wl = __builtin_fmaf(xc, 4.0e-9f, 1550.0e-9f);
        float h  = rc.K2 * xc * fastrcp(wl);
        float fr = fastfract(h);
        cth[cc] = cos2pi(fr);
        sth[cc] = sin2pi(fr);
      }
    }
#pragma unroll
    for (int n = 0; n <= NRING; ++n) {
      __syncthreads();   // previous MFMA reads done before overwriting LDS
      // stage B tile for (ring n, islice is)
      const int kbase = n * 512 + ks * 128 + is * 64;
#pragma unroll
      for (int p = 0; p < 4; ++p)
        gl_lds16(gb0 + (size_t)p * 32 * KTOT + kbase, lB + p * 4096);
      // generate A tile (bf16) into swizzled LDS
      if (n < NRING) {
        const float Crn = rc.Cr[n], Snn = rc.Snr[n];
#pragma unroll
        for (int g = 0; g < 4; ++g) {
          short8 wv;
#pragma unroll
          for (int e = 0; e < 8; ++e) {
            const int cc = g * 8 + e;
            float cph = __builtin_fmaf(cth[cc], Crn, sth[cc] * Snn);
            float den = __builtin_fmaf(rc.qn, cph, rc.s);
            float T   = __builtin_fmaf(rc.P, fastrcp(den), 1.0f);
            wv[e] = (short)f2bf(T);
          }
          *reinterpret_cast<short8*>((char*)As + wb[g]) = wv;
        }
      } else {  // residual ring: raw (unclipped) x
#pragma unroll
        for (int g = 0; g < 4; ++g) {
          short8 wv;
#pragma unroll
          for (int e = 0; e < 8; ++e) wv[e] = (short)f2bf(xr[g * 8 + e]);
          *reinterpret_cast<short8*>((char*)As + wb[g]) = wv;
        }
      }
      __syncthreads();   // drains vmcnt (B) + lgkmcnt (A writes)
      // ---- MFMA: K=64 for this (ring, islice) ----
#pragma unroll
      for (int kk = 0; kk < 2; ++kk) {
        const char* pA = kk ? pA1 : pA0;
        const char* pB = kk ? pB1 : pB0;
        short8 af[4], bf[4];
#pragma unroll
        for (int m = 0; m < 4; ++m)
          af[m] = *reinterpret_cast<const short8*>(pA + m * 2048);
#pragma unroll
        for (int q = 0; q < 4; ++q)
          bf[q] = *reinterpret_cast<const short8*>(pB + q * 2048);
#pragma unroll
        for (int m = 0; m < 4; ++m)
#pragma unroll
          for (int q = 0; q < 4; ++q)
            acc[m][q] = __builtin_amdgcn_mfma_f32_16x16x32_bf16(af[m], bf[q], acc[m][q], 0, 0, 0);
      }
    }
  }

  float* po = part + (size_t)ks * ((size_t)Bsz * OUTsz);
  const int r0 = brow + wr * 64 + ((lane >> 4) * 4);
  const int c0 = bcol + wc * 64 + (lane & 15);
#pragma unroll
  for (int m = 0; m < 4; ++m)
#pragma unroll
    for (int q = 0; q < 4; ++q)
#pragma unroll
      for (int e = 0; e < 4; ++e)
        po[(size_t)(r0 + m * 16 + e) * OUTsz + (c0 + q * 16)] = acc[m][q][e];
}

// ---- reduce 4 split-K partials + kl ----
__global__ __launch_bounds__(256) void reduce_kernel(
    const f32x4* __restrict__ part, float* __restrict__ out) {
  const size_t idx = (size_t)blockIdx.x * 256 + threadIdx.x;
  const size_t stride = (size_t)Bsz * OUTsz / 4;
  f32x4 v = part[idx] + part[idx + stride] + part[idx + 2 * stride] + part[idx + 3 * stride];
  reinterpret_cast<f32x4*>(out)[idx] = v;
  if (idx == 0) out[(size_t)Bsz * OUTsz] = 0.0f;   // kl
}

extern "C" void kernel_launch(void* const* d_in, const int* in_sizes, int n_in,
                              void* d_out, int out_size, void* d_ws, size_t ws_size,
                              hipStream_t stream) {
  const float* x      = (const float*)d_in[0];
  const float* coeffs = (const float*)d_in[1];
  const float* bw     = (const float*)d_in[2];
  float* out = (float*)d_out;

  unsigned short* Bt = (unsigned short*)d_ws;                         // 8,912,896 B
  float* part = (float*)((char*)d_ws + (size_t)OUTsz * KTOT * 2);     // 33,554,432 B

  RC rc;
  {
    const double PI  = 3.14159265358979323846;
    const double Lc  = 2.0 * PI * 30.0e-6;
    const double WL0 = 1550.0e-9;
    const double NG  = 4.2;
    const double Aamp = pow(10.0, -3.0 * (Lc * 100.0) / 20.0);
    const double Rt2  = 0.8;                       // r_t^2
    const double Rt   = sqrt(Rt2);
    for (int r = 0; r < NRING; ++r) {
      double off  = -PI + r * (2.0 * PI / 15.0);
      double neff = 2.34 + off * WL0 / (2.0 * PI * Lc);
      double rev0 = (Lc / WL0) * neff;             // phase at wl=WL0 [rev]
      rc.Cr[r]  = (float)cos(2.0 * PI * rev0);
      rc.Snr[r] = (float)(-sin(2.0 * PI * rev0));
    }
    rc.K2 = (float)(-4.0e-9 * Lc * NG / WL0);      // h = K2*xc/wl
    rc.qn = (float)(-2.0 * Rt * Aamp);
    rc.s  = (float)(1.0 + Rt2 * Aamp * Aamp);
    rc.P  = (float)(-(1.0 - Aamp * Aamp) * (1.0 - Rt2));
  }

  hipLaunchKernelGGL(pack_b_kernel, dim3((INsz * OUTsz) / 256), dim3(256), 0, stream,
                     coeffs, bw, Bt);
  hipLaunchKernelGGL(gemm_fused_kernel, dim3(32 * 4 * SPLITK), dim3(256), 0, stream,
                     x, Bt, part, rc);
  hipLaunchKernelGGL(reduce_kernel, dim3((Bsz * OUTsz / 4) / 256), dim3(256), 0, stream,
                     (const f32x4*)part, out);
}

// Round 4
// 62.250 us; speedup vs baseline: 1.5806x; 1.2720x over previous
//
#include <hip/hip_runtime.h>
#include <hip/hip_bf16.h>
#include <cmath>
#include <cstdint>

#define Bsz   4096
#define INsz  512
#define OUTsz 512
#define NRING 16
#define KTOT  8704          /* IN*(NR+1): residual folded in as 17th slot */
#define SPLITK 4
#define NPH   34            /* 2 i-halves x 17 rings, K=64 each */

using short8 = __attribute__((ext_vector_type(8))) short;
using f32x4  = __attribute__((ext_vector_type(4))) float;

struct RC {
  float Cr[NRING];    // cos(2*pi*rev0_r)
  float Snr[NRING];   // -sin(2*pi*rev0_r)
  float K2, SQ, pad0, pad1;  // h=K2*xc*rcp(wl); A' = rcp(cph + SQ)
};

__device__ __forceinline__ unsigned short f2bf(float f) {
  __hip_bfloat16 h = __float2bfloat16(f);               // native cvt (RNE)
  return *reinterpret_cast<unsigned short*>(&h);
}
__device__ __forceinline__ float fastrcp(float x) {
#if __has_builtin(__builtin_amdgcn_rcpf)
  return __builtin_amdgcn_rcpf(x);
#else
  return 1.0f / x;
#endif
}
__device__ __forceinline__ float fastfract(float x) {
#if __has_builtin(__builtin_amdgcn_fractf)
  return __builtin_amdgcn_fractf(x);
#else
  return x - floorf(x);
#endif
}
__device__ __forceinline__ float cos2pi(float fr) {
#if __has_builtin(__builtin_amdgcn_cosf)
  return __builtin_amdgcn_cosf(fr);
#else
  return __cosf(fr * 6.28318530717958647692f);
#endif
}
__device__ __forceinline__ float sin2pi(float fr) {
#if __has_builtin(__builtin_amdgcn_sinf)
  return __builtin_amdgcn_sinf(fr);
#else
  return __sinf(fr * 6.28318530717958647692f);
#endif
}

__device__ __forceinline__ void gl_lds16(const void* g, void* l) {
  __builtin_amdgcn_global_load_lds(
      (const __attribute__((address_space(1))) void*)g,
      (__attribute__((address_space(3))) void*)l, 16, 0, 0);
}

// ---- pack B'^T: [OUT][KTOT] bf16, k = n*512 + i; also bias[o] = sum coeffs ----
__global__ __launch_bounds__(512) void pack_b_kernel(
    const float* __restrict__ coeffs, const float* __restrict__ bw,
    unsigned short* __restrict__ Bt, float* __restrict__ bias, float PQ) {
  __shared__ float red[8];
  const int o = blockIdx.x;        // 512 blocks
  const int i = threadIdx.x;       // 512 threads
  const float* cp = coeffs + ((size_t)i * OUTsz + o) * NRING;  // 64B contiguous
  unsigned short* row = Bt + (size_t)o * KTOT + i;
  float s = 0.0f;
#pragma unroll
  for (int j = 0; j < 4; ++j) {
    f32x4 v = *reinterpret_cast<const f32x4*>(cp + j * 4);
#pragma unroll
    for (int e = 0; e < 4; ++e) {
      const int n = j * 4 + e;
      s += v[e];
      row[(size_t)n * INsz] = f2bf(PQ * v[e]);
    }
  }
  row[(size_t)NRING * INsz] = f2bf(bw[(size_t)i * OUTsz + o]);  // residual unscaled
  // block-reduce s over 512 threads -> bias[o]
#pragma unroll
  for (int off = 32; off > 0; off >>= 1) s += __shfl_down(s, off);
  const int w = i >> 6;
  if ((i & 63) == 0) red[w] = s;
  __syncthreads();
  if (i == 0) {
    float t = 0.0f;
#pragma unroll
    for (int k = 0; k < 8; ++k) t += red[k];
    bias[o] = t;
  }
}

// ---- fused basis-gen + split-K bf16 MFMA GEMM, BM=128 x BN=256, 8 waves ----
// k = n*512 + i; block ks owns i-range [ks*128,(ks+1)*128).
// LDS: As[2][128][64] (16KB x2) + Bs[3][256][64] (32KB x3) = 128KB dynamic.
// Schedule: 2-deep B prefetch, counted vmcnt(4), 1 barrier/phase (T3+T4+T5).
__global__ __launch_bounds__(512) void gemm_fused_kernel(
    const float* __restrict__ x, const unsigned short* __restrict__ Bt,
    float* __restrict__ part, RC rc) {
  extern __shared__ char smem[];
  char* smA = smem;            // 2 x 16384
  char* smB = smem + 32768;    // 3 x 32768
  const int tid  = threadIdx.x;
  const int lane = tid & 63;
  const int w    = tid >> 6;
  const int bid  = blockIdx.x;
  const int cbks = bid & 7;          // -> XCD id (same Bt slice co-resident)
  const int rb   = bid >> 3;         // 0..31
  const int cb   = cbks & 1, ks = cbks >> 1;
  const int brow = rb * 128, bcol = cb * 256;

  // --- A-gen ownership: row r (0..127), i-quarter q4 (16 i's) ---
  const int r  = tid & 127;
  const int q4 = tid >> 7;
  const int wb0 = r * 128 + (((q4 * 2 + 0) ^ (r & 7)) * 16);
  const int wb1 = r * 128 + (((q4 * 2 + 1) ^ (r & 7)) * 16);

  // --- B staging: pre-swizzled per-lane global source, linear LDS dest ---
  const int cg = (lane & 7) ^ ((lane >> 3) & 7);
  const unsigned short* gb0 = Bt + (size_t)(bcol + w * 8 + (lane >> 3)) * KTOT + cg * 8;

  // --- fragment read geometry: 8 waves = 2M x 4N, each 64x64 output ---
  const int wr = w >> 2, wc = w & 3;
  const int l7 = lane & 7;
  const int rowA = wr * 64 + (lane & 15);
  const int rowB = wc * 64 + (lane & 15);

  // --- prologue: hoist ALL x loads + trig (no vmem in main loop except gl_lds) ---
  float xr[32], cth[32], sth[32];
  const float* gx = x + (size_t)(brow + r) * INsz + ks * 128 + q4 * 16;
#pragma unroll
  for (int h = 0; h < 2; ++h)
#pragma unroll
    for (int j = 0; j < 4; ++j) {
      f32x4 v = *reinterpret_cast<const f32x4*>(gx + h * 64 + j * 4);
#pragma unroll
      for (int e = 0; e < 4; ++e) xr[h * 16 + j * 4 + e] = v[e];
    }
#pragma unroll
  for (int c = 0; c < 32; ++c) {
    float xc = fminf(fmaxf(xr[c], -1.0f), 1.0f);
    float wl = __builtin_fmaf(xc, 4.0e-9f, 1550.0e-9f);
    float hh = rc.K2 * xc * fastrcp(wl);
    float fr = fastfract(hh);
    cth[c] = cos2pi(fr);
    sth[c] = sin2pi(fr);
  }

  auto STAGE = [&](int p) {   // issue 4 gl_lds for B-tile of phase p
    const int is = (p >= 17) ? 1 : 0, n = p - 17 * is;
    const size_t koff = (size_t)(n * 512 + ks * 128 + is * 64);
    char* ldst = smB + (p % 3) * 32768 + w * 1024;
    const unsigned short* src = gb0 + koff;
#pragma unroll
    for (int iss = 0; iss < 4; ++iss)
      gl_lds16(src + (size_t)iss * 64 * KTOT, ldst + iss * 8192);
  };
  auto GENA = [&](int p) {    // generate A-tile of phase p into As[p&1]
    const int is = (p >= 17) ? 1 : 0, n = p - 17 * is;
    char* dst = smA + (p & 1) * 16384;
    if (n < NRING) {
      const float Crn = rc.Cr[n], Snn = rc.Snr[n];
#pragma unroll
      for (int g = 0; g < 2; ++g) {
        short8 wv;
#pragma unroll
        for (int e = 0; e < 8; ++e) {
          const int c = is * 16 + g * 8 + e;
          float cph = __builtin_fmaf(cth[c], Crn, sth[c] * Snn);
          wv[e] = (short)f2bf(fastrcp(cph + rc.SQ));
        }
        *reinterpret_cast<short8*>(dst + (g ? wb1 : wb0)) = wv;
      }
    } else {                  // residual ring: raw (unclipped) x
#pragma unroll
      for (int g = 0; g < 2; ++g) {
        short8 wv;
#pragma unroll
        for (int e = 0; e < 8; ++e) wv[e] = (short)f2bf(xr[is * 16 + g * 8 + e]);
        *reinterpret_cast<short8*>(dst + (g ? wb1 : wb0)) = wv;
      }
    }
  };

  f32x4 acc[4][4];
#pragma unroll
  for (int m = 0; m < 4; ++m)
#pragma unroll
    for (int q = 0; q < 4; ++q) acc[m][q] = (f32x4){0.f, 0.f, 0.f, 0.f};

  STAGE(0); STAGE(1);
  GENA(0);
  asm volatile("s_waitcnt vmcnt(4) lgkmcnt(0)" ::: "memory");
  __builtin_amdgcn_s_barrier();
  __builtin_amdgcn_sched_barrier(0);

#pragma unroll
  for (int p = 0; p < NPH; ++p) {
    if (p + 2 < NPH) STAGE(p + 2);
    const char* bA = smA + (p & 1) * 16384;
    const char* bB = smB + (p % 3) * 32768;
    short8 af[2][4], bfr[2][4];
#pragma unroll
    for (int kk = 0; kk < 2; ++kk) {
      const int oct = (((lane >> 4) + kk * 4) ^ l7) * 16;
#pragma unroll
      for (int m = 0; m < 4; ++m)
        af[kk][m] = *reinterpret_cast<const short8*>(bA + (rowA + m * 16) * 128 + oct);
#pragma unroll
      for (int q = 0; q < 4; ++q)
        bfr[kk][q] = *reinterpret_cast<const short8*>(bB + (rowB + q * 16) * 128 + oct);
    }
    if (p + 1 < NPH) GENA(p + 1);
    __builtin_amdgcn_s_setprio(1);
#pragma unroll
    for (int kk = 0; kk < 2; ++kk)
#pragma unroll
      for (int m = 0; m < 4; ++m)
#pragma unroll
        for (int q = 0; q < 4; ++q)
          acc[m][q] = __builtin_amdgcn_mfma_f32_16x16x32_bf16(af[kk][m], bfr[kk][q], acc[m][q], 0, 0, 0);
    __builtin_amdgcn_s_setprio(0);
    if (p + 1 < NPH) {
      if (p + 2 < NPH) {
        asm volatile("s_waitcnt vmcnt(4) lgkmcnt(0)" ::: "memory");  // B(p+1) done, B(p+2) in flight
      } else {
        asm volatile("s_waitcnt vmcnt(0) lgkmcnt(0)" ::: "memory");  // drain for last phase
      }
      __builtin_amdgcn_s_barrier();
      __builtin_amdgcn_sched_barrier(0);
    }
  }

  float* po = part + (size_t)ks * ((size_t)Bsz * OUTsz);
  const int r0 = brow + wr * 64 + ((lane >> 4) * 4);
  const int c0 = bcol + wc * 64 + (lane & 15);
#pragma unroll
  for (int m = 0; m < 4; ++m)
#pragma unroll
    for (int q = 0; q < 4; ++q)
#pragma unroll
      for (int e = 0; e < 4; ++e)
        po[(size_t)(r0 + m * 16 + e) * OUTsz + (c0 + q * 16)] = acc[m][q][e];
}

// ---- reduce 4 split-K partials + bias + kl ----
__global__ __launch_bounds__(256) void reduce_kernel(
    const f32x4* __restrict__ part, const f32x4* __restrict__ bias,
    float* __restrict__ out) {
  const size_t idx = (size_t)blockIdx.x * 256 + threadIdx.x;
  const size_t stride = (size_t)Bsz * OUTsz / 4;
  f32x4 v = part[idx] + part[idx + stride] + part[idx + 2 * stride] + part[idx + 3 * stride];
  v = v + bias[idx & 127];
  reinterpret_cast<f32x4*>(out)[idx] = v;
  if (idx == 0) out[(size_t)Bsz * OUTsz] = 0.0f;   // kl
}

extern "C" void kernel_launch(void* const* d_in, const int* in_sizes, int n_in,
                              void* d_out, int out_size, void* d_ws, size_t ws_size,
                              hipStream_t stream) {
  const float* x      = (const float*)d_in[0];
  const float* coeffs = (const float*)d_in[1];
  const float* bw     = (const float*)d_in[2];
  float* out = (float*)d_out;

  unsigned short* Bt = (unsigned short*)d_ws;                              // 8,912,896 B
  float* part = (float*)((char*)d_ws + (size_t)OUTsz * KTOT * 2);          // 33,554,432 B
  float* bias = (float*)((char*)d_ws + (size_t)OUTsz * KTOT * 2
                                     + (size_t)SPLITK * Bsz * OUTsz * 4);  // 2048 B

  RC rc;
  float PQ;
  {
    const double PI  = 3.14159265358979323846;
    const double Lc  = 2.0 * PI * 30.0e-6;
    const double WL0 = 1550.0e-9;
    const double NG  = 4.2;
    const double Aamp = pow(10.0, -3.0 * (Lc * 100.0) / 20.0);
    const double Rt2  = 0.8;
    const double Rt   = sqrt(Rt2);
    for (int rr = 0; rr < NRING; ++rr) {
      double off  = -PI + rr * (2.0 * PI / 15.0);
      double neff = 2.34 + off * WL0 / (2.0 * PI * Lc);
      double rev0 = (Lc / WL0) * neff;
      rc.Cr[rr]  = (float)cos(2.0 * PI * rev0);
      rc.Snr[rr] = (float)(-sin(2.0 * PI * rev0));
    }
    const double qn = -2.0 * Rt * Aamp;
    const double s  = 1.0 + Rt2 * Aamp * Aamp;
    const double P  = -(1.0 - Aamp * Aamp) * (1.0 - Rt2);
    rc.K2 = (float)(-4.0e-9 * Lc * NG / WL0);
    rc.SQ = (float)(s / qn);
    rc.pad0 = rc.pad1 = 0.f;
    PQ = (float)(P / qn);
  }

  hipFuncSetAttribute(reinterpret_cast<const void*>(gemm_fused_kernel),
                      hipFuncAttributeMaxDynamicSharedMemorySize, 131072);

  hipLaunchKernelGGL(pack_b_kernel, dim3(OUTsz), dim3(512), 0, stream,
                     coeffs, bw, Bt, bias, PQ);
  hipLaunchKernelGGL(gemm_fused_kernel, dim3(256), dim3(512), 131072, stream,
                     x, Bt, part, rc);
  hipLaunchKernelGGL(reduce_kernel, dim3((Bsz * OUTsz / 4) / 256), dim3(256), 0, stream,
                     (const f32x4*)part, (const f32x4*)bias, out);
}